// Round 3
// baseline (110.905 us; speedup 1.0000x reference)
//
#include <hip/hip_runtime.h>

// TropConv2D: out[b,ho,wo,f] = max_k(patch_k + w[k,f]) - min_k(patch_k + w[k,f])
// x: (8,32,32,32) f32 NHWC, w: (288,64) f32, out: (8,30,30,64) f32
// k = (i*3 + j)*32 + c   (TF extract_patches ordering)
//
// v3: latency + VALU-count attack.
//   - All 72 weights/wave preloaded into VGPRs in ONE batched window
//     (v2 paid 9 serial ~300cyc L2 windows per wave).
//   - px outer loop (dynamic 6/8), ij fully unrolled against reg weights;
//     per-pixel accumulators are scalars, written straight to LDS partials.
//   - 3-3-3 fmaxf trees with accumulator folded in -> v_max3_f32 formation:
//     16 VALU per px*ij (8 add + 4 max3 + 4 min3), the op-count floor.
//   grid = 8*30*4 = 960 blocks, 256 thr = 4 waves; lane=filter, wave=chan slice.
//   Max/min associative -> channel-split partials exact (absmax 0 expected).

#define C_IN 32
#define NF 64
#define H_OUT 30
#define W_OUT 30
#define W_IN 32

__global__ __launch_bounds__(256, 4) void tropconv_kernel(
    const float* __restrict__ x,
    const float* __restrict__ w,
    float* __restrict__ out) {
    const int bx = blockIdx.x;            // 0..959
    const int q = bx & 3;                 // row quarter
    const int bho = bx >> 2;              // b*30 + ho
    const int b = bho / H_OUT;
    const int ho = bho - b * H_OUT;
    const int tid = threadIdx.x;
    const int lane = tid & 63;            // filter index
    const int wave = tid >> 6;            // channel-slice 0..3

    const int col0 = q * 8;
    const int npx = (q == 3) ? 6 : 8;     // block-uniform
    const int ncols = (q == 3) ? 8 : 10;

    __shared__ __align__(16) float xs[3 * 10 * C_IN];  // 3.75 KB patch tile
    __shared__ float pmx[4][8][NF];                    // 8 KB partial max
    __shared__ float pmn[4][8][NF];                    // 8 KB partial min

    // ---- Preload this wave's 72 weights (one batched latency window) ----
    // w[(ij*32 + wave*8 + cc)*64 + lane]
    float wreg[72];
    {
        const float* __restrict__ wp = w + (size_t)(wave * 8) * NF + lane;
        #pragma unroll
        for (int ij = 0; ij < 9; ++ij)
            #pragma unroll
            for (int cc = 0; cc < 8; ++cc)
                wreg[ij * 8 + cc] = wp[(ij * C_IN + cc) * NF];
    }

    // ---- Stage patch rows (contiguous NHWC segments) ----
    {
        const int nf4_row = ncols * (C_IN / 4);    // 80 or 64 float4 per row
        const int total_f4 = 3 * nf4_row;          // 240 or 192
        if (tid < total_f4) {
            const int r = tid / nf4_row;
            const int cc = tid - r * nf4_row;
            const float4* __restrict__ src = (const float4*)(
                x + ((size_t)((b * 32 + ho + r) * W_IN + col0)) * C_IN);
            ((float4*)xs)[r * 80 + cc] = src[cc];
        }
    }
    __syncthreads();

    for (int px = 0; px < npx; ++px) {
        float mx = -INFINITY, mn = INFINITY;
        #pragma unroll
        for (int ij = 0; ij < 9; ++ij) {
            const int i = ij / 3;
            const int j = ij - i * 3;
            const float* __restrict__ pp =
                xs + (i * 10 + (px + j)) * C_IN + wave * 8;
            float4 p0 = ((const float4*)pp)[0];   // broadcast ds_read_b128
            float4 p1 = ((const float4*)pp)[1];
            float s0 = p0.x + wreg[ij * 8 + 0];
            float s1 = p0.y + wreg[ij * 8 + 1];
            float s2 = p0.z + wreg[ij * 8 + 2];
            float s3 = p0.w + wreg[ij * 8 + 3];
            float s4 = p1.x + wreg[ij * 8 + 4];
            float s5 = p1.y + wreg[ij * 8 + 5];
            float s6 = p1.z + wreg[ij * 8 + 6];
            float s7 = p1.w + wreg[ij * 8 + 7];
            // 3-3-3 trees with accumulator folded in -> 4x v_max3 / v_min3
            float a0 = fmaxf(fmaxf(s0, s1), s2);
            float a1 = fmaxf(fmaxf(s3, s4), s5);
            float a2 = fmaxf(fmaxf(s6, s7), mx);
            mx = fmaxf(fmaxf(a0, a1), a2);
            float b0 = fminf(fminf(s0, s1), s2);
            float b1 = fminf(fminf(s3, s4), s5);
            float b2 = fminf(fminf(s6, s7), mn);
            mn = fminf(fminf(b0, b1), b2);
        }
        pmx[wave][px][lane] = mx;
        pmn[wave][px][lane] = mn;
    }
    __syncthreads();

    // ---- Cross-wave combine (exact: max/min associative) ----
    const int nout = npx * NF;            // 512 or 384
    for (int e = tid; e < nout; e += 256) {
        const int px = e >> 6;
        const int f = e & 63;
        float a = fmaxf(fmaxf(pmx[0][px][f], pmx[1][px][f]),
                        fmaxf(pmx[2][px][f], pmx[3][px][f]));
        float m = fminf(fminf(pmn[0][px][f], pmn[1][px][f]),
                        fminf(pmn[2][px][f], pmn[3][px][f]));
        out[((size_t)bho * W_OUT + (col0 + px)) * NF + f] = a - m;
    }
}

extern "C" void kernel_launch(void* const* d_in, const int* in_sizes, int n_in,
                              void* d_out, int out_size, void* d_ws, size_t ws_size,
                              hipStream_t stream) {
    const float* x = (const float*)d_in[0];   // 8*32*32*32
    const float* w = (const float*)d_in[1];   // 288*64
    float* out = (float*)d_out;               // 8*30*30*64

    dim3 grid(8 * H_OUT * 4);                 // 960 blocks
    dim3 block(256);
    tropconv_kernel<<<grid, block, 0, stream>>>(x, w, out);
}